// Round 1
// baseline (733.778 us; speedup 1.0000x reference)
//
#include <hip/hip_runtime.h>
#include <hip/hip_bf16.h>
#include <cstdint>

typedef unsigned short u16;
typedef __attribute__((ext_vector_type(8))) short bf16x8;
typedef __attribute__((ext_vector_type(4))) float f32x4;

#define B_ROWS 16384
#define N_HID  1024
#define K_DIM  6144
#define EMB    128

__device__ __forceinline__ u16 f2bf(float x) {
  union { float f; uint32_t u; } v; v.f = x;
  uint32_t r = v.u + 0x7fffu + ((v.u >> 16) & 1u);   // round-to-nearest-even
  return (u16)(r >> 16);
}

__global__ void init_out_kernel(float* __restrict__ out, const float* __restrict__ b_o) {
  int i = blockIdx.x * blockDim.x + threadIdx.x;
  if (i < B_ROWS * 3) out[i] = b_o[i % 3];
}

// W_h (K_DIM x N_HID f32, row-major) -> Wt (N_HID x K_DIM bf16, row-major)
__global__ void transpose_wh_kernel(const float* __restrict__ Wh, u16* __restrict__ Wt) {
  __shared__ float tile[32][33];
  int k0 = blockIdx.x * 32, n0 = blockIdx.y * 32;
  int tx = threadIdx.x & 31, ty = threadIdx.x >> 5;  // 32 x 8
  #pragma unroll
  for (int j = 0; j < 4; ++j)
    tile[ty + j * 8][tx] = Wh[(size_t)(k0 + ty + j * 8) * N_HID + n0 + tx];
  __syncthreads();
  #pragma unroll
  for (int j = 0; j < 4; ++j)
    Wt[(size_t)(n0 + ty + j * 8) * K_DIM + k0 + tx] = f2bf(tile[tx][ty + j * 8]);
}

// Fused: gather(bf16 cast) -> GEMM1(bf16 MFMA) -> +b_h, relu -> @W_o -> atomicAdd out
template <bool USE_WT>
__global__ __launch_bounds__(256, 2) void fused_parser_kernel(
    const int* __restrict__ word_ids, const int* __restrict__ tag_ids,
    const int* __restrict__ dep_ids,  const float* __restrict__ wordE,
    const float* __restrict__ tagE,   const float* __restrict__ depE,
    const float* __restrict__ Wh,     const u16* __restrict__ Wt,
    const float* __restrict__ b_h,    const float* __restrict__ W_o,
    float* __restrict__ out) {
  __shared__ u16 As[128 * 72];  // 128 rows x 64 k, stride 72 (pad)
  __shared__ u16 Bs[128 * 72];  // 128 n    x 64 k, stride 72 (pad)

  const int tid  = threadIdx.x;
  const int lane = tid & 63;
  const int wid  = tid >> 6;
  const int wr   = wid >> 1, wc = wid & 1;   // 2x2 waves, 64x64 each
  const int bm0  = blockIdx.y * 128;
  const int bn0  = blockIdx.x * 128;

  f32x4 acc[4][4] = {};

  const int r    = tid & 127;   // staging row
  const int half = tid >> 7;    // 0/1 -> k-halves of 32

  for (int kt = 0; kt < K_DIM / 64; ++kt) {
    __syncthreads();
    // ---- stage A: gather embedding rows, f32 -> bf16 ----
    {
      int f  = kt >> 1;             // feature 0..47 (64 cols = half a feature)
      int e0 = (kt & 1) << 6;       // 0 or 64
      int brow = bm0 + r;
      int id; const float* table;
      if (f < 18)      { id = word_ids[brow * 18 + f];        table = wordE; }
      else if (f < 36) { id = tag_ids[brow * 18 + (f - 18)];  table = tagE;  }
      else             { id = dep_ids[brow * 12 + (f - 36)];  table = depE;  }
      const float4* src = (const float4*)(table + (size_t)id * EMB + e0 + half * 32);
      u16* dst = &As[r * 72 + half * 32];
      #pragma unroll
      for (int j = 0; j < 4; ++j) {
        float4 v0 = src[2 * j], v1 = src[2 * j + 1];
        bf16x8 w;
        w[0] = (short)f2bf(v0.x); w[1] = (short)f2bf(v0.y);
        w[2] = (short)f2bf(v0.z); w[3] = (short)f2bf(v0.w);
        w[4] = (short)f2bf(v1.x); w[5] = (short)f2bf(v1.y);
        w[6] = (short)f2bf(v1.z); w[7] = (short)f2bf(v1.w);
        *(bf16x8*)(dst + j * 8) = w;
      }
    }
    // ---- stage B: W_h^T tile ----
    if (USE_WT) {
      const bf16x8* src = (const bf16x8*)(Wt + (size_t)(bn0 + r) * K_DIM + kt * 64 + half * 32);
      u16* dst = &Bs[r * 72 + half * 32];
      #pragma unroll
      for (int j = 0; j < 4; ++j) *(bf16x8*)(dst + j * 8) = src[j];
    } else {
      int kk = tid >> 2, q = tid & 3;
      const float4* src = (const float4*)(Wh + (size_t)(kt * 64 + kk) * N_HID + bn0 + q * 32);
      #pragma unroll
      for (int j = 0; j < 8; ++j) {
        float4 v = src[j];
        int nb = q * 32 + j * 4;
        Bs[(nb + 0) * 72 + kk] = f2bf(v.x);
        Bs[(nb + 1) * 72 + kk] = f2bf(v.y);
        Bs[(nb + 2) * 72 + kk] = f2bf(v.z);
        Bs[(nb + 3) * 72 + kk] = f2bf(v.w);
      }
    }
    __syncthreads();
    // ---- compute: 2 k-slices of 32, 4x4 frags ----
    const u16* pa = &As[(wr * 64 + (lane & 15)) * 72 + ((lane >> 4) * 8)];
    const u16* pb = &Bs[(wc * 64 + (lane & 15)) * 72 + ((lane >> 4) * 8)];
    #pragma unroll
    for (int ks = 0; ks < 2; ++ks) {
      bf16x8 a[4], b[4];
      #pragma unroll
      for (int m = 0; m < 4; ++m) a[m] = *(const bf16x8*)(pa + m * 16 * 72 + ks * 32);
      #pragma unroll
      for (int n = 0; n < 4; ++n) b[n] = *(const bf16x8*)(pb + n * 16 * 72 + ks * 32);
      #pragma unroll
      for (int m = 0; m < 4; ++m)
        #pragma unroll
        for (int n = 0; n < 4; ++n)
          acc[m][n] = __builtin_amdgcn_mfma_f32_16x16x32_bf16(a[m], b[n], acc[m][n], 0, 0, 0);
    }
  }

  // ---- epilogue: h = relu(acc + b_h); out[row] += h @ W_o (3 cols) ----
  float bh[4], wo[4][3];
  #pragma unroll
  for (int n = 0; n < 4; ++n) {
    int j = bn0 + wc * 64 + n * 16 + (lane & 15);
    bh[n] = b_h[j];
    wo[n][0] = W_o[j * 3 + 0]; wo[n][1] = W_o[j * 3 + 1]; wo[n][2] = W_o[j * 3 + 2];
  }
  #pragma unroll
  for (int m = 0; m < 4; ++m) {
    #pragma unroll
    for (int reg = 0; reg < 4; ++reg) {
      float p0 = 0.f, p1 = 0.f, p2 = 0.f;
      #pragma unroll
      for (int n = 0; n < 4; ++n) {
        float h = acc[m][n][reg] + bh[n];
        h = fmaxf(h, 0.f);
        p0 += h * wo[n][0]; p1 += h * wo[n][1]; p2 += h * wo[n][2];
      }
      #pragma unroll
      for (int mask = 1; mask < 16; mask <<= 1) {
        p0 += __shfl_xor(p0, mask);
        p1 += __shfl_xor(p1, mask);
        p2 += __shfl_xor(p2, mask);
      }
      if ((lane & 15) == 0) {
        int row = bm0 + wr * 64 + m * 16 + ((lane >> 4) << 2) + reg;
        atomicAdd(&out[row * 3 + 0], p0);
        atomicAdd(&out[row * 3 + 1], p1);
        atomicAdd(&out[row * 3 + 2], p2);
      }
    }
  }
}

extern "C" void kernel_launch(void* const* d_in, const int* in_sizes, int n_in,
                              void* d_out, int out_size, void* d_ws, size_t ws_size,
                              hipStream_t stream) {
  const int*   word_ids = (const int*)d_in[0];
  const int*   tag_ids  = (const int*)d_in[1];
  const int*   dep_ids  = (const int*)d_in[2];
  const float* wordE    = (const float*)d_in[3];
  const float* tagE     = (const float*)d_in[4];
  const float* depE     = (const float*)d_in[5];
  const float* Wh       = (const float*)d_in[6];
  const float* b_h      = (const float*)d_in[7];
  const float* W_o      = (const float*)d_in[8];
  const float* b_o      = (const float*)d_in[9];
  float*       out      = (float*)d_out;

  const size_t WT_BYTES = (size_t)N_HID * K_DIM * sizeof(u16);  // 12.6 MB
  const bool use_wt = (ws_size >= WT_BYTES) && (d_ws != nullptr);
  u16* Wt = (u16*)d_ws;

  init_out_kernel<<<(B_ROWS * 3 + 255) / 256, 256, 0, stream>>>(out, b_o);

  dim3 grid(N_HID / 128, B_ROWS / 128);  // (8, 128)
  if (use_wt) {
    transpose_wh_kernel<<<dim3(K_DIM / 32, N_HID / 32), 256, 0, stream>>>(Wh, Wt);
    fused_parser_kernel<true><<<grid, 256, 0, stream>>>(
        word_ids, tag_ids, dep_ids, wordE, tagE, depE, Wh, Wt, b_h, W_o, out);
  } else {
    fused_parser_kernel<false><<<grid, 256, 0, stream>>>(
        word_ids, tag_ids, dep_ids, wordE, tagE, depE, Wh, Wt, b_h, W_o, out);
  }
}

// Round 3
// 345.354 us; speedup vs baseline: 2.1247x; 2.1247x over previous
//
#include <hip/hip_runtime.h>
#include <hip/hip_bf16.h>
#include <cstdint>

typedef unsigned short u16;
typedef __attribute__((ext_vector_type(8))) short bf16x8;
typedef __attribute__((ext_vector_type(4))) float f32x4;

#define B_ROWS 16384
#define N_HID  1024
#define K_DIM  6144
#define EMB    128
#define N_WORD 100000
#define N_TAG  48
#define N_DEP  40

__device__ __forceinline__ u16 f2bf(float x) {
  union { float f; uint32_t u; } v; v.f = x;
  uint32_t r = v.u + 0x7fffu + ((v.u >> 16) & 1u);   // round-to-nearest-even
  return (u16)(r >> 16);
}

__device__ __forceinline__ void gload_lds16(const void* g, void* l) {
  __builtin_amdgcn_global_load_lds(
      (const __attribute__((address_space(1))) void*)g,
      (__attribute__((address_space(3))) void*)l, 16, 0, 0);
}

__global__ void init_out_kernel(float* __restrict__ out, const float* __restrict__ b_o) {
  int i = blockIdx.x * blockDim.x + threadIdx.x;
  if (i < B_ROWS * 3) out[i] = b_o[i % 3];
}

// W_h (K_DIM x N_HID f32, row-major) -> Wt (N_HID x K_DIM bf16, row-major)
__global__ void transpose_wh_kernel(const float* __restrict__ Wh, u16* __restrict__ Wt) {
  __shared__ float tile[32][33];
  int k0 = blockIdx.x * 32, n0 = blockIdx.y * 32;
  int tx = threadIdx.x & 31, ty = threadIdx.x >> 5;  // 32 x 8
  #pragma unroll
  for (int j = 0; j < 4; ++j)
    tile[ty + j * 8][tx] = Wh[(size_t)(k0 + ty + j * 8) * N_HID + n0 + tx];
  __syncthreads();
  #pragma unroll
  for (int j = 0; j < 4; ++j)
    Wt[(size_t)(n0 + ty + j * 8) * K_DIM + k0 + tx] = f2bf(tile[tx][ty + j * 8]);
}

// cast all three embedding tables f32 -> bf16 (unit of work: 8 elements)
__global__ void cast_tables_kernel(const float* __restrict__ wordE, const float* __restrict__ tagE,
                                   const float* __restrict__ depE, u16* __restrict__ wordB,
                                   u16* __restrict__ tagB, u16* __restrict__ depB) {
  const int W8 = N_WORD * EMB / 8, T8 = N_TAG * EMB / 8, D8 = N_DEP * EMB / 8;
  int i = blockIdx.x * blockDim.x + threadIdx.x;
  const float* src; u16* dst; int j;
  if (i < W8)            { src = wordE; dst = wordB; j = i; }
  else if (i < W8 + T8)  { src = tagE;  dst = tagB;  j = i - W8; }
  else if (i < W8 + T8 + D8) { src = depE; dst = depB; j = i - W8 - T8; }
  else return;
  const float4* s = (const float4*)(src + (size_t)j * 8);
  float4 v0 = s[0], v1 = s[1];
  bf16x8 w;
  w[0] = (short)f2bf(v0.x); w[1] = (short)f2bf(v0.y);
  w[2] = (short)f2bf(v0.z); w[3] = (short)f2bf(v0.w);
  w[4] = (short)f2bf(v1.x); w[5] = (short)f2bf(v1.y);
  w[6] = (short)f2bf(v1.z); w[7] = (short)f2bf(v1.w);
  *(bf16x8*)(dst + (size_t)j * 8) = w;
}

// ---------------- v2: global_load_lds + XOR-swizzled LDS, bf16 tables ----------------
__global__ __launch_bounds__(256, 4) void fused_v2_kernel(
    const int* __restrict__ word_ids, const int* __restrict__ tag_ids,
    const int* __restrict__ dep_ids,  const u16* __restrict__ wordB,
    const u16* __restrict__ tagB,     const u16* __restrict__ depB,
    const u16* __restrict__ Wt,       const float* __restrict__ b_h,
    const float* __restrict__ W_o,    float* __restrict__ out) {
  __shared__ u16 As[128 * 64];  // [row][k] linear, swizzle applied on SOURCE+READ
  __shared__ u16 Bs[128 * 64];  // [n][k]   linear

  const int tid  = threadIdx.x;
  const int lane = tid & 63;
  const int wid  = tid >> 6;
  const int wr   = wid >> 1, wc = wid & 1;   // 2x2 waves, 64x64 each
  const int bm0  = blockIdx.y * 128;
  const int bn0  = blockIdx.x * 128;

  f32x4 acc[4][4] = {};

  for (int kt = 0; kt < K_DIM / 64; ++kt) {
    __syncthreads();  // previous compute done before overwriting LDS
    // ---- stage A: gathered embedding rows (bf16), swizzled source, linear dest ----
    {
      int f = kt >> 1, e0 = (kt & 1) << 6;
      const int* ids; const u16* tbl; int nf, fl;
      if (f < 18)      { ids = word_ids; tbl = wordB; nf = 18; fl = f; }
      else if (f < 36) { ids = tag_ids;  tbl = tagB;  nf = 18; fl = f - 18; }
      else             { ids = dep_ids;  tbl = depB;  nf = 12; fl = f - 36; }
      #pragma unroll
      for (int it = 0; it < 4; ++it) {
        int cidx = wid * 256 + it * 64 + lane;   // 16B-chunk index in tile (1024 total)
        int r = cidx >> 3, c = cidx & 7;
        int id = ids[(bm0 + r) * nf + fl];
        const u16* src = tbl + (size_t)id * EMB + e0 + ((c ^ (r & 7)) << 3);
        gload_lds16(src, &As[(wid * 256 + it * 64) * 8]);
      }
    }
    // ---- stage B: W_h^T tile, swizzled source, linear dest ----
    #pragma unroll
    for (int it = 0; it < 4; ++it) {
      int cidx = wid * 256 + it * 64 + lane;
      int rn = cidx >> 3, c = cidx & 7;
      const u16* src = Wt + (size_t)(bn0 + rn) * K_DIM + kt * 64 + ((c ^ (rn & 7)) << 3);
      gload_lds16(src, &Bs[(wid * 256 + it * 64) * 8]);
    }
    __syncthreads();  // drains vmcnt (compiler emits s_waitcnt before s_barrier)
    // ---- compute: 2 k-slices of 32, 4x4 frags, swizzled reads ----
    const int l15 = lane & 15, ca = lane >> 4;
    #pragma unroll
    for (int ks = 0; ks < 2; ++ks) {
      bf16x8 a[4], b[4];
      #pragma unroll
      for (int m = 0; m < 4; ++m) {
        int ra = wr * 64 + m * 16 + l15;
        int ch = (ca + ks * 4) ^ (ra & 7);
        a[m] = *(const bf16x8*)&As[ra * 64 + ch * 8];
      }
      #pragma unroll
      for (int n = 0; n < 4; ++n) {
        int rb = wc * 64 + n * 16 + l15;
        int ch = (ca + ks * 4) ^ (rb & 7);
        b[n] = *(const bf16x8*)&Bs[rb * 64 + ch * 8];
      }
      #pragma unroll
      for (int m = 0; m < 4; ++m)
        #pragma unroll
        for (int n = 0; n < 4; ++n)
          acc[m][n] = __builtin_amdgcn_mfma_f32_16x16x32_bf16(a[m], b[n], acc[m][n], 0, 0, 0);
    }
  }

  // ---- epilogue: h = relu(acc + b_h); out[row] += h @ W_o ----
  float bh[4], wo[4][3];
  #pragma unroll
  for (int n = 0; n < 4; ++n) {
    int j = bn0 + wc * 64 + n * 16 + (lane & 15);
    bh[n] = b_h[j];
    wo[n][0] = W_o[j * 3 + 0]; wo[n][1] = W_o[j * 3 + 1]; wo[n][2] = W_o[j * 3 + 2];
  }
  #pragma unroll
  for (int m = 0; m < 4; ++m) {
    #pragma unroll
    for (int reg = 0; reg < 4; ++reg) {
      float p0 = 0.f, p1 = 0.f, p2 = 0.f;
      #pragma unroll
      for (int n = 0; n < 4; ++n) {
        float h = acc[m][n][reg] + bh[n];
        h = fmaxf(h, 0.f);
        p0 += h * wo[n][0]; p1 += h * wo[n][1]; p2 += h * wo[n][2];
      }
      #pragma unroll
      for (int mask = 1; mask < 16; mask <<= 1) {
        p0 += __shfl_xor(p0, mask);
        p1 += __shfl_xor(p1, mask);
        p2 += __shfl_xor(p2, mask);
      }
      if ((lane & 15) == 0) {
        int row = bm0 + wr * 64 + m * 16 + ((lane >> 4) << 2) + reg;
        atomicAdd(&out[row * 3 + 0], p0);
        atomicAdd(&out[row * 3 + 1], p1);
        atomicAdd(&out[row * 3 + 2], p2);
      }
    }
  }
}

// ---------------- round-1 fallback (f32 gather, padded LDS) ----------------
template <bool USE_WT>
__global__ __launch_bounds__(256, 2) void fused_parser_kernel(
    const int* __restrict__ word_ids, const int* __restrict__ tag_ids,
    const int* __restrict__ dep_ids,  const float* __restrict__ wordE,
    const float* __restrict__ tagE,   const float* __restrict__ depE,
    const float* __restrict__ Wh,     const u16* __restrict__ Wt,
    const float* __restrict__ b_h,    const float* __restrict__ W_o,
    float* __restrict__ out) {
  __shared__ u16 As[128 * 72];
  __shared__ u16 Bs[128 * 72];
  const int tid  = threadIdx.x;
  const int lane = tid & 63;
  const int wid  = tid >> 6;
  const int wr   = wid >> 1, wc = wid & 1;
  const int bm0  = blockIdx.y * 128;
  const int bn0  = blockIdx.x * 128;
  f32x4 acc[4][4] = {};
  const int r    = tid & 127;
  const int half = tid >> 7;

  for (int kt = 0; kt < K_DIM / 64; ++kt) {
    __syncthreads();
    {
      int f  = kt >> 1;
      int e0 = (kt & 1) << 6;
      int brow = bm0 + r;
      int id; const float* table;
      if (f < 18)      { id = word_ids[brow * 18 + f];        table = wordE; }
      else if (f < 36) { id = tag_ids[brow * 18 + (f - 18)];  table = tagE;  }
      else             { id = dep_ids[brow * 12 + (f - 36)];  table = depE;  }
      const float4* src = (const float4*)(table + (size_t)id * EMB + e0 + half * 32);
      u16* dst = &As[r * 72 + half * 32];
      #pragma unroll
      for (int j = 0; j < 4; ++j) {
        float4 v0 = src[2 * j], v1 = src[2 * j + 1];
        bf16x8 w;
        w[0] = (short)f2bf(v0.x); w[1] = (short)f2bf(v0.y);
        w[2] = (short)f2bf(v0.z); w[3] = (short)f2bf(v0.w);
        w[4] = (short)f2bf(v1.x); w[5] = (short)f2bf(v1.y);
        w[6] = (short)f2bf(v1.z); w[7] = (short)f2bf(v1.w);
        *(bf16x8*)(dst + j * 8) = w;
      }
    }
    if (USE_WT) {
      const bf16x8* src = (const bf16x8*)(Wt + (size_t)(bn0 + r) * K_DIM + kt * 64 + half * 32);
      u16* dst = &Bs[r * 72 + half * 32];
      #pragma unroll
      for (int j = 0; j < 4; ++j) *(bf16x8*)(dst + j * 8) = src[j];
    } else {
      int kk = tid >> 2, q = tid & 3;
      const float4* src = (const float4*)(Wh + (size_t)(kt * 64 + kk) * N_HID + bn0 + q * 32);
      #pragma unroll
      for (int j = 0; j < 8; ++j) {
        float4 v = src[j];
        int nb = q * 32 + j * 4;
        Bs[(nb + 0) * 72 + kk] = f2bf(v.x);
        Bs[(nb + 1) * 72 + kk] = f2bf(v.y);
        Bs[(nb + 2) * 72 + kk] = f2bf(v.z);
        Bs[(nb + 3) * 72 + kk] = f2bf(v.w);
      }
    }
    __syncthreads();
    const u16* pa = &As[(wr * 64 + (lane & 15)) * 72 + ((lane >> 4) * 8)];
    const u16* pb = &Bs[(wc * 64 + (lane & 15)) * 72 + ((lane >> 4) * 8)];
    #pragma unroll
    for (int ks = 0; ks < 2; ++ks) {
      bf16x8 a[4], b[4];
      #pragma unroll
      for (int m = 0; m < 4; ++m) a[m] = *(const bf16x8*)(pa + m * 16 * 72 + ks * 32);
      #pragma unroll
      for (int n = 0; n < 4; ++n) b[n] = *(const bf16x8*)(pb + n * 16 * 72 + ks * 32);
      #pragma unroll
      for (int m = 0; m < 4; ++m)
        #pragma unroll
        for (int n = 0; n < 4; ++n)
          acc[m][n] = __builtin_amdgcn_mfma_f32_16x16x32_bf16(a[m], b[n], acc[m][n], 0, 0, 0);
    }
  }

  float bh[4], wo[4][3];
  #pragma unroll
  for (int n = 0; n < 4; ++n) {
    int j = bn0 + wc * 64 + n * 16 + (lane & 15);
    bh[n] = b_h[j];
    wo[n][0] = W_o[j * 3 + 0]; wo[n][1] = W_o[j * 3 + 1]; wo[n][2] = W_o[j * 3 + 2];
  }
  #pragma unroll
  for (int m = 0; m < 4; ++m) {
    #pragma unroll
    for (int reg = 0; reg < 4; ++reg) {
      float p0 = 0.f, p1 = 0.f, p2 = 0.f;
      #pragma unroll
      for (int n = 0; n < 4; ++n) {
        float h = acc[m][n][reg] + bh[n];
        h = fmaxf(h, 0.f);
        p0 += h * wo[n][0]; p1 += h * wo[n][1]; p2 += h * wo[n][2];
      }
      #pragma unroll
      for (int mask = 1; mask < 16; mask <<= 1) {
        p0 += __shfl_xor(p0, mask);
        p1 += __shfl_xor(p1, mask);
        p2 += __shfl_xor(p2, mask);
      }
      if ((lane & 15) == 0) {
        int row = bm0 + wr * 64 + m * 16 + ((lane >> 4) << 2) + reg;
        atomicAdd(&out[row * 3 + 0], p0);
        atomicAdd(&out[row * 3 + 1], p1);
        atomicAdd(&out[row * 3 + 2], p2);
      }
    }
  }
}

extern "C" void kernel_launch(void* const* d_in, const int* in_sizes, int n_in,
                              void* d_out, int out_size, void* d_ws, size_t ws_size,
                              hipStream_t stream) {
  const int*   word_ids = (const int*)d_in[0];
  const int*   tag_ids  = (const int*)d_in[1];
  const int*   dep_ids  = (const int*)d_in[2];
  const float* wordE    = (const float*)d_in[3];
  const float* tagE     = (const float*)d_in[4];
  const float* depE     = (const float*)d_in[5];
  const float* Wh       = (const float*)d_in[6];
  const float* b_h      = (const float*)d_in[7];
  const float* W_o      = (const float*)d_in[8];
  const float* b_o      = (const float*)d_in[9];
  float*       out      = (float*)d_out;

  const size_t WT_ELEMS   = (size_t)N_HID * K_DIM;            // bf16
  const size_t WORD_ELEMS = (size_t)N_WORD * EMB;
  const size_t TAG_ELEMS  = (size_t)N_TAG * EMB;
  const size_t DEP_ELEMS  = (size_t)N_DEP * EMB;
  const size_t NEED_V2 = (WT_ELEMS + WORD_ELEMS + TAG_ELEMS + DEP_ELEMS) * sizeof(u16);
  const size_t NEED_WT = WT_ELEMS * sizeof(u16);

  u16* Wt    = (u16*)d_ws;
  u16* wordB = Wt + WT_ELEMS;
  u16* tagB  = wordB + WORD_ELEMS;
  u16* depB  = tagB + TAG_ELEMS;

  init_out_kernel<<<(B_ROWS * 3 + 255) / 256, 256, 0, stream>>>(out, b_o);

  dim3 grid(N_HID / 128, B_ROWS / 128);  // (8, 128)
  if (d_ws && ws_size >= NEED_V2) {
    transpose_wh_kernel<<<dim3(K_DIM / 32, N_HID / 32), 256, 0, stream>>>(Wh, Wt);
    const int CAST8 = (int)((WORD_ELEMS + TAG_ELEMS + DEP_ELEMS) / 8);
    cast_tables_kernel<<<(CAST8 + 255) / 256, 256, 0, stream>>>(wordE, tagE, depE, wordB, tagB, depB);
    fused_v2_kernel<<<grid, 256, 0, stream>>>(
        word_ids, tag_ids, dep_ids, wordB, tagB, depB, Wt, b_h, W_o, out);
  } else if (d_ws && ws_size >= NEED_WT) {
    transpose_wh_kernel<<<dim3(K_DIM / 32, N_HID / 32), 256, 0, stream>>>(Wh, Wt);
    fused_parser_kernel<true><<<grid, 256, 0, stream>>>(
        word_ids, tag_ids, dep_ids, wordE, tagE, depE, Wh, Wt, b_h, W_o, out);
  } else {
    fused_parser_kernel<false><<<grid, 256, 0, stream>>>(
        word_ids, tag_ids, dep_ids, wordE, tagE, depE, Wh, Wt, b_h, W_o, out);
  }
}

// Round 4
// 325.144 us; speedup vs baseline: 2.2568x; 1.0622x over previous
//
#include <hip/hip_runtime.h>
#include <hip/hip_bf16.h>
#include <cstdint>

typedef unsigned short u16;
typedef __attribute__((ext_vector_type(8))) short bf16x8;
typedef __attribute__((ext_vector_type(4))) float f32x4;

#define B_ROWS 16384
#define N_HID  1024
#define K_DIM  6144
#define EMB    128
#define N_WORD 100000
#define N_TAG  48
#define N_DEP  40
#define NTILES 96
#define NITER  48

__device__ __forceinline__ u16 f2bf(float x) {
  union { float f; uint32_t u; } v; v.f = x;
  uint32_t r = v.u + 0x7fffu + ((v.u >> 16) & 1u);
  return (u16)(r >> 16);
}

__device__ __forceinline__ void gload_lds16(const void* g, void* l) {
  __builtin_amdgcn_global_load_lds(
      (const __attribute__((address_space(1))) void*)g,
      (__attribute__((address_space(3))) void*)l, 16, 0, 0);
}

#define SBAR do { \
  __builtin_amdgcn_sched_barrier(0); \
  asm volatile("" ::: "memory"); \
  __builtin_amdgcn_s_barrier(); \
  asm volatile("" ::: "memory"); \
  __builtin_amdgcn_sched_barrier(0); \
} while (0)

__global__ void init_out_kernel(float* __restrict__ out, const float* __restrict__ b_o) {
  int i = blockIdx.x * blockDim.x + threadIdx.x;
  if (i < B_ROWS * 3) out[i] = b_o[i % 3];
}

// W_h (K_DIM x N_HID f32) -> Wt (N_HID x K_DIM bf16)
__global__ void transpose_wh_kernel(const float* __restrict__ Wh, u16* __restrict__ Wt) {
  __shared__ float tile[32][33];
  int k0 = blockIdx.x * 32, n0 = blockIdx.y * 32;
  int tx = threadIdx.x & 31, ty = threadIdx.x >> 5;
  #pragma unroll
  for (int j = 0; j < 4; ++j)
    tile[ty + j * 8][tx] = Wh[(size_t)(k0 + ty + j * 8) * N_HID + n0 + tx];
  __syncthreads();
  #pragma unroll
  for (int j = 0; j < 4; ++j)
    Wt[(size_t)(n0 + ty + j * 8) * K_DIM + k0 + tx] = f2bf(tile[tx][ty + j * 8]);
}

// cast 3 embedding tables f32 -> bf16 (concatenated dest)
__global__ void cast_tables_kernel(const float* __restrict__ wordE, const float* __restrict__ tagE,
                                   const float* __restrict__ depE, u16* __restrict__ tblB) {
  const int W8 = N_WORD * EMB / 8, T8 = N_TAG * EMB / 8, D8 = N_DEP * EMB / 8;
  int i = blockIdx.x * blockDim.x + threadIdx.x;
  const float* src; int j;
  if (i < W8)                { src = wordE; j = i; }
  else if (i < W8 + T8)      { src = tagE;  j = i - W8; }
  else if (i < W8 + T8 + D8) { src = depE;  j = i - W8 - T8; }
  else return;
  const float4* s = (const float4*)(src + (size_t)j * 8);
  float4 v0 = s[0], v1 = s[1];
  bf16x8 w;
  w[0] = (short)f2bf(v0.x); w[1] = (short)f2bf(v0.y);
  w[2] = (short)f2bf(v0.z); w[3] = (short)f2bf(v0.w);
  w[4] = (short)f2bf(v1.x); w[5] = (short)f2bf(v1.y);
  w[6] = (short)f2bf(v1.z); w[7] = (short)f2bf(v1.w);
  *(bf16x8*)(tblB + (size_t)i * 8) = w;
}

// offv[f][row] = elem offset of gathered row in concatenated tblB
__global__ void build_offv_kernel(const int* __restrict__ w, const int* __restrict__ t,
                                  const int* __restrict__ d, int* __restrict__ offv) {
  int row = blockIdx.x * 256 + threadIdx.x;
  int f = blockIdx.y;
  if (row >= B_ROWS) return;
  int off;
  if (f < 18)      off = w[row * 18 + f] * EMB;
  else if (f < 36) off = N_WORD * EMB + t[row * 18 + (f - 18)] * EMB;
  else             off = (N_WORD + N_TAG) * EMB + d[row * 12 + (f - 36)] * EMB;
  offv[f * B_ROWS + row] = off;
}

__device__ __forceinline__ void rd_b4(const u16* base, int sch, bf16x8* q) {
  #pragma unroll
  for (int nf = 0; nf < 4; ++nf) q[nf] = *(const bf16x8*)(base + nf * 1024 + sch);
}
__device__ __forceinline__ void rd_a4(const u16* base, int sch, int mh, bf16x8* q) {
  #pragma unroll
  for (int mf = 0; mf < 4; ++mf) q[mf] = *(const bf16x8*)(base + (mh * 4 + mf) * 1024 + sch);
}
__device__ __forceinline__ void mfma16(f32x4 (&acc)[8][4], int mh, const bf16x8* aT, const bf16x8* bq) {
  #pragma unroll
  for (int m = 0; m < 4; ++m)
    #pragma unroll
    for (int n = 0; n < 4; ++n)
      acc[mh * 4 + m][n] = __builtin_amdgcn_mfma_f32_16x16x32_bf16(aT[m], bq[n], acc[mh * 4 + m][n], 0, 0, 0);
}

// ---------------- v3: 256x256 tile, 8-phase counted-vmcnt pipeline ----------------
__global__ __launch_bounds__(512, 2) void fused_v3_kernel(
    const u16* __restrict__ tblB, const int* __restrict__ offv,
    const u16* __restrict__ Wt,   const float* __restrict__ b_h,
    const float* __restrict__ W_o, float* __restrict__ out) {
  __shared__ u16 As[2][256 * 64];
  __shared__ u16 Bs[2][256 * 64];

  const int tid  = threadIdx.x;
  const int lane = tid & 63;
  const int wid  = tid >> 6;        // 0..7
  const int wr   = wid >> 2;        // 0..1
  const int wc   = wid & 3;         // 0..3
  const int bn0  = blockIdx.x * 256;
  const int bm0  = blockIdx.y * 256;
  const int l15  = lane & 15, ca = lane >> 4;

  // staging constants: chunk = tid + issue*512; row = chunk>>3, col = chunk&7
  const int r0 = tid >> 3;          // 0..63
  const int c  = tid & 7;
  const int sc = ((c ^ (r0 & 7)) << 3);   // swizzled k-offset (elems)
  const u16* Bp[4];
  #pragma unroll
  for (int j = 0; j < 4; ++j)
    Bp[j] = Wt + (size_t)(bn0 + j * 64 + r0) * K_DIM + sc;
  const int ivb = bm0 + r0;

#define DESTA(buf, h, is) ((void*)&As[buf][(h) * 8192 + (is) * 4096 + wid * 512])
#define DESTB(buf, h, is) ((void*)&Bs[buf][(h) * 8192 + (is) * 4096 + wid * 512])
#define STAGE_B2(buf, h, t) do { \
    gload_lds16(Bp[2 * (h)] + (size_t)(t) * 64, DESTB(buf, h, 0)); \
    gload_lds16(Bp[2 * (h) + 1] + (size_t)(t) * 64, DESTB(buf, h, 1)); } while (0)
#define STAGE_A2(buf, h, e0) do { \
    gload_lds16(tblB + (size_t)oA[2 * (h)] + (e0) + sc, DESTA(buf, h, 0)); \
    gload_lds16(tblB + (size_t)oA[2 * (h) + 1] + (e0) + sc, DESTA(buf, h, 1)); } while (0)

  // frag-read bases
  const u16* aBase0 = &As[0][(wr * 128 + l15) * 64];
  const u16* aBase1 = &As[1][(wr * 128 + l15) * 64];
  const u16* bBase0 = &Bs[0][(wc * 64 + l15) * 64];
  const u16* bBase1 = &Bs[1][(wc * 64 + l15) * 64];
  const int sch0 = ((ca    ) ^ (l15 & 7)) << 3;
  const int sch1 = ((ca + 4) ^ (l15 & 7)) << 3;

  f32x4 acc[8][4] = {};
  int oA[4];

  // ---- prologue: stage B(0), ids f=0, A(0), B(1); gate tile0+A landed ----
  STAGE_B2(0, 0, 0); STAGE_B2(0, 1, 0);
  #pragma unroll
  for (int j = 0; j < 4; ++j) oA[j] = offv[ivb + j * 64];
  STAGE_A2(0, 0, 0); STAGE_A2(0, 1, 0);     // tile 0 (e0 = 0)
  STAGE_B2(1, 0, 1); STAGE_B2(1, 1, 1);
  asm volatile("s_waitcnt vmcnt(4)" ::: "memory");
  SBAR;

  #pragma unroll 1
  for (int i = 0; i < NITER; ++i) {
    const int T = 2 * i;
    bf16x8 bq0[4], bq1[4], aT[4];
    // ---- ph1: tile T ks0 mh0; stage A0(T+1) ----
    rd_b4(bBase0, sch0, bq0);
    rd_a4(aBase0, sch0, 0, aT);
    STAGE_A2(1, 0, 64);
    SBAR;
    __builtin_amdgcn_s_setprio(1); mfma16(acc, 0, aT, bq0); __builtin_amdgcn_s_setprio(0);
    SBAR;
    // ---- ph2: ks0 mh1; stage A1(T+1) ----
    rd_b4(bBase0, sch1, bq1);
    rd_a4(aBase0, sch0, 1, aT);
    STAGE_A2(1, 1, 64);
    SBAR;
    __builtin_amdgcn_s_setprio(1); mfma16(acc, 1, aT, bq0); __builtin_amdgcn_s_setprio(0);
    SBAR;
    // ---- ph3: ks1 mh0; ids f=i+1; stage B0(T+2) ----
    if (i + 1 < NITER) {
      const int* ov = offv + (i + 1) * B_ROWS + ivb;
      #pragma unroll
      for (int j = 0; j < 4; ++j) oA[j] = ov[j * 64];
    }
    rd_a4(aBase0, sch1, 0, aT);
    if (T + 2 < NTILES) STAGE_B2(0, 0, T + 2);
    SBAR;
    __builtin_amdgcn_s_setprio(1); mfma16(acc, 0, aT, bq1); __builtin_amdgcn_s_setprio(0);
    SBAR;
    // ---- ph4: ks1 mh1; stage B1(T+2); GATE ----
    rd_a4(aBase0, sch1, 1, aT);
    if (T + 2 < NTILES) STAGE_B2(0, 1, T + 2);
    if (i == NITER - 1) { asm volatile("s_waitcnt vmcnt(0)" ::: "memory"); }
    else                { asm volatile("s_waitcnt vmcnt(8)" ::: "memory"); }
    SBAR;
    __builtin_amdgcn_s_setprio(1); mfma16(acc, 1, aT, bq1); __builtin_amdgcn_s_setprio(0);
    SBAR;
    // ---- ph5: tile T+1 ks0 mh0; stage A0(T+2) ----
    rd_b4(bBase1, sch0, bq0);
    rd_a4(aBase1, sch0, 0, aT);
    if (T + 2 < NTILES) STAGE_A2(0, 0, 0);
    SBAR;
    __builtin_amdgcn_s_setprio(1); mfma16(acc, 0, aT, bq0); __builtin_amdgcn_s_setprio(0);
    SBAR;
    // ---- ph6: ks0 mh1; stage A1(T+2) ----
    rd_b4(bBase1, sch1, bq1);
    rd_a4(aBase1, sch0, 1, aT);
    if (T + 2 < NTILES) STAGE_A2(0, 1, 0);
    SBAR;
    __builtin_amdgcn_s_setprio(1); mfma16(acc, 1, aT, bq0); __builtin_amdgcn_s_setprio(0);
    SBAR;
    // ---- ph7: ks1 mh0; stage B0(T+3) ----
    rd_a4(aBase1, sch1, 0, aT);
    if (T + 3 < NTILES) STAGE_B2(1, 0, T + 3);
    SBAR;
    __builtin_amdgcn_s_setprio(1); mfma16(acc, 0, aT, bq1); __builtin_amdgcn_s_setprio(0);
    SBAR;
    // ---- ph8: ks1 mh1; stage B1(T+3); GATE ----
    rd_a4(aBase1, sch1, 1, aT);
    if (T + 3 < NTILES) STAGE_B2(1, 1, T + 3);
    asm volatile("s_waitcnt vmcnt(4)" ::: "memory");
    SBAR;
    __builtin_amdgcn_s_setprio(1); mfma16(acc, 1, aT, bq1); __builtin_amdgcn_s_setprio(0);
    SBAR;
  }

  // ---- epilogue: h = relu(acc + b_h); out += h @ W_o ----
  float bh[4], wo[4][3];
  #pragma unroll
  for (int nf = 0; nf < 4; ++nf) {
    int j = bn0 + wc * 64 + nf * 16 + l15;
    bh[nf] = b_h[j];
    wo[nf][0] = W_o[j * 3 + 0]; wo[nf][1] = W_o[j * 3 + 1]; wo[nf][2] = W_o[j * 3 + 2];
  }
  #pragma unroll
  for (int mf = 0; mf < 8; ++mf) {
    #pragma unroll
    for (int reg = 0; reg < 4; ++reg) {
      float p0 = 0.f, p1 = 0.f, p2 = 0.f;
      #pragma unroll
      for (int nf = 0; nf < 4; ++nf) {
        float h = acc[mf][nf][reg] + bh[nf];
        h = fmaxf(h, 0.f);
        p0 += h * wo[nf][0]; p1 += h * wo[nf][1]; p2 += h * wo[nf][2];
      }
      #pragma unroll
      for (int mask = 1; mask < 16; mask <<= 1) {
        p0 += __shfl_xor(p0, mask);
        p1 += __shfl_xor(p1, mask);
        p2 += __shfl_xor(p2, mask);
      }
      if (l15 == 0) {
        int row = bm0 + wr * 128 + mf * 16 + (ca << 2) + reg;
        atomicAdd(&out[row * 3 + 0], p0);
        atomicAdd(&out[row * 3 + 1], p1);
        atomicAdd(&out[row * 3 + 2], p2);
      }
    }
  }
#undef DESTA
#undef DESTB
#undef STAGE_B2
#undef STAGE_A2
}

// ---------------- v2 fallback (R3-proven): 128x128, 2-barrier loop ----------------
__global__ __launch_bounds__(256, 4) void fused_v2_kernel(
    const int* __restrict__ word_ids, const int* __restrict__ tag_ids,
    const int* __restrict__ dep_ids,  const u16* __restrict__ tblB,
    const u16* __restrict__ Wt,       const float* __restrict__ b_h,
    const float* __restrict__ W_o,    float* __restrict__ out) {
  __shared__ u16 As2[128 * 64];
  __shared__ u16 Bs2[128 * 64];
  const int tid  = threadIdx.x;
  const int lane = tid & 63;
  const int wid  = tid >> 6;
  const int wr   = wid >> 1, wc = wid & 1;
  const int bm0  = blockIdx.y * 128;
  const int bn0  = blockIdx.x * 128;
  f32x4 acc[4][4] = {};

  for (int kt = 0; kt < K_DIM / 64; ++kt) {
    __syncthreads();
    {
      int f = kt >> 1, e0 = (kt & 1) << 6;
      const int* ids; int nf, fl; size_t tb;
      if (f < 18)      { ids = word_ids; nf = 18; fl = f;      tb = 0; }
      else if (f < 36) { ids = tag_ids;  nf = 18; fl = f - 18; tb = (size_t)N_WORD * EMB; }
      else             { ids = dep_ids;  nf = 12; fl = f - 36; tb = (size_t)(N_WORD + N_TAG) * EMB; }
      #pragma unroll
      for (int it = 0; it < 4; ++it) {
        int cidx = wid * 256 + it * 64 + lane;
        int r = cidx >> 3, cc = cidx & 7;
        int id = ids[(bm0 + r) * nf + fl];
        const u16* src = tblB + tb + (size_t)id * EMB + e0 + ((cc ^ (r & 7)) << 3);
        gload_lds16(src, &As2[(wid * 256 + it * 64) * 8]);
      }
    }
    #pragma unroll
    for (int it = 0; it < 4; ++it) {
      int cidx = wid * 256 + it * 64 + lane;
      int rn = cidx >> 3, cc = cidx & 7;
      const u16* src = Wt + (size_t)(bn0 + rn) * K_DIM + kt * 64 + ((cc ^ (rn & 7)) << 3);
      gload_lds16(src, &Bs2[(wid * 256 + it * 64) * 8]);
    }
    __syncthreads();
    const int l15 = lane & 15, ca = lane >> 4;
    #pragma unroll
    for (int ks = 0; ks < 2; ++ks) {
      bf16x8 a[4], b[4];
      #pragma unroll
      for (int m = 0; m < 4; ++m) {
        int ra = wr * 64 + m * 16 + l15;
        int ch = (ca + ks * 4) ^ (ra & 7);
        a[m] = *(const bf16x8*)&As2[ra * 64 + ch * 8];
      }
      #pragma unroll
      for (int n = 0; n < 4; ++n) {
        int rb = wc * 64 + n * 16 + l15;
        int ch = (ca + ks * 4) ^ (rb & 7);
        b[n] = *(const bf16x8*)&Bs2[rb * 64 + ch * 8];
      }
      #pragma unroll
      for (int m = 0; m < 4; ++m)
        #pragma unroll
        for (int n = 0; n < 4; ++n)
          acc[m][n] = __builtin_amdgcn_mfma_f32_16x16x32_bf16(a[m], b[n], acc[m][n], 0, 0, 0);
    }
  }

  const int l15 = lane & 15;
  float bh[4], wo[4][3];
  #pragma unroll
  for (int n = 0; n < 4; ++n) {
    int j = bn0 + wc * 64 + n * 16 + l15;
    bh[n] = b_h[j];
    wo[n][0] = W_o[j * 3 + 0]; wo[n][1] = W_o[j * 3 + 1]; wo[n][2] = W_o[j * 3 + 2];
  }
  #pragma unroll
  for (int m = 0; m < 4; ++m) {
    #pragma unroll
    for (int reg = 0; reg < 4; ++reg) {
      float p0 = 0.f, p1 = 0.f, p2 = 0.f;
      #pragma unroll
      for (int n = 0; n < 4; ++n) {
        float h = acc[m][n][reg] + bh[n];
        h = fmaxf(h, 0.f);
        p0 += h * wo[n][0]; p1 += h * wo[n][1]; p2 += h * wo[n][2];
      }
      #pragma unroll
      for (int mask = 1; mask < 16; mask <<= 1) {
        p0 += __shfl_xor(p0, mask);
        p1 += __shfl_xor(p1, mask);
        p2 += __shfl_xor(p2, mask);
      }
      if (l15 == 0) {
        int row = bm0 + wr * 64 + m * 16 + ((lane >> 4) << 2) + reg;
        atomicAdd(&out[row * 3 + 0], p0);
        atomicAdd(&out[row * 3 + 1], p1);
        atomicAdd(&out[row * 3 + 2], p2);
      }
    }
  }
}

extern "C" void kernel_launch(void* const* d_in, const int* in_sizes, int n_in,
                              void* d_out, int out_size, void* d_ws, size_t ws_size,
                              hipStream_t stream) {
  const int*   word_ids = (const int*)d_in[0];
  const int*   tag_ids  = (const int*)d_in[1];
  const int*   dep_ids  = (const int*)d_in[2];
  const float* wordE    = (const float*)d_in[3];
  const float* tagE     = (const float*)d_in[4];
  const float* depE     = (const float*)d_in[5];
  const float* Wh       = (const float*)d_in[6];
  const float* b_h      = (const float*)d_in[7];
  const float* W_o      = (const float*)d_in[8];
  const float* b_o      = (const float*)d_in[9];
  float*       out      = (float*)d_out;

  const size_t WT_ELEMS  = (size_t)N_HID * K_DIM;
  const size_t TBL_ELEMS = (size_t)(N_WORD + N_TAG + N_DEP) * EMB;
  const size_t OFFV_ELEMS = (size_t)48 * B_ROWS;
  const size_t NEED_V2 = (WT_ELEMS + TBL_ELEMS) * sizeof(u16);
  const size_t NEED_V3 = NEED_V2 + OFFV_ELEMS * sizeof(int);

  u16* Wt   = (u16*)d_ws;
  u16* tblB = Wt + WT_ELEMS;
  int* offv = (int*)(tblB + TBL_ELEMS);

  init_out_kernel<<<(B_ROWS * 3 + 255) / 256, 256, 0, stream>>>(out, b_o);

  if (d_ws && ws_size >= NEED_V3) {
    transpose_wh_kernel<<<dim3(K_DIM / 32, N_HID / 32), 256, 0, stream>>>(Wh, Wt);
    cast_tables_kernel<<<(int)((TBL_ELEMS / 8 + 255) / 256), 256, 0, stream>>>(wordE, tagE, depE, tblB);
    build_offv_kernel<<<dim3(B_ROWS / 256, 48), 256, 0, stream>>>(word_ids, tag_ids, dep_ids, offv);
    fused_v3_kernel<<<dim3(N_HID / 256, B_ROWS / 256), 512, 0, stream>>>(
        tblB, offv, Wt, b_h, W_o, out);
  } else if (d_ws && ws_size >= NEED_V2) {
    transpose_wh_kernel<<<dim3(K_DIM / 32, N_HID / 32), 256, 0, stream>>>(Wh, Wt);
    cast_tables_kernel<<<(int)((TBL_ELEMS / 8 + 255) / 256), 256, 0, stream>>>(wordE, tagE, depE, tblB);
    fused_v2_kernel<<<dim3(N_HID / 128, B_ROWS / 128), 256, 0, stream>>>(
        word_ids, tag_ids, dep_ids, tblB, Wt, b_h, W_o, out);
  }
}